// Round 5
// baseline (540.845 us; speedup 1.0000x reference)
//
#include <hip/hip_runtime.h>
#include <math.h>

#define HW   2816           // 32*88
#define IMGS 6
#define DD   59
#define NV   16384          // 128*128 BEV cells (B=1)
#define COUT 128
#define NPIX (IMGS*HW)      // 16896
#define WCUT 1e-5f

typedef _Float16 half8  __attribute__((ext_vector_type(8)));
typedef _Float16 half2v __attribute__((ext_vector_type(2)));
typedef float f32x4 __attribute__((ext_vector_type(4)));

__device__ __forceinline__ void glds16(const _Float16* g, const _Float16* l){
    __builtin_amdgcn_global_load_lds(
        (const __attribute__((address_space(1))) void*)g,
        (__attribute__((address_space(3))) void*)l, 16, 0, 0);
}

// ---------------- fused prep: zero | wsplit x3 | bn_prep ----------------

__device__ __forceinline__ void wsplit_body(const float* __restrict__ w,
                                            _Float16* __restrict__ wh,
                                            _Float16* __restrict__ wl,
                                            int idx, int CO, int CI, int KK){
    if (idx >= CO*CI*KK) return;
    int co  = idx/(CI*KK);
    int r   = idx - co*CI*KK;
    int ci  = r/KK;
    int tap = r - ci*KK;
    float v = w[idx];
    _Float16 h = (_Float16)v;
    size_t o = ((size_t)tap*CO + co)*CI + ci;
    wh[o] = h; wl[o] = (_Float16)(v - (float)h);
}

__global__ void prep_kernel(int* __restrict__ zp, int nz,
                            const float* __restrict__ w1, _Float16* wh1, _Float16* wl1,
                            const float* __restrict__ w2, _Float16* wh2, _Float16* wl2,
                            const float* __restrict__ w3, _Float16* wh3, _Float16* wl3,
                            const float* __restrict__ c1b, const float* __restrict__ g1,
                            const float* __restrict__ bb1, const float* __restrict__ m1,
                            const float* __restrict__ v1,
                            const float* __restrict__ c2b, const float* __restrict__ g2,
                            const float* __restrict__ bb2, const float* __restrict__ m2,
                            const float* __restrict__ v2,
                            float* __restrict__ s1, float* __restrict__ t1,
                            float* __restrict__ s2, float* __restrict__ t2){
    int b = blockIdx.x, t = threadIdx.x;
    if (b < 129){
        int i = b*256 + t;
        if (i < nz) zp[i] = 0;
    } else if (b < 129 + 2304){
        wsplit_body(w1, wh1, wl1, (b-129)*256 + t, 256, 256, 9);
    } else if (b < 129 + 4608){
        wsplit_body(w2, wh2, wl2, (b-2433)*256 + t, 256, 256, 9);
    } else if (b < 129 + 4736){
        wsplit_body(w3, wh3, wl3, (b-4737)*256 + t, 128, 256, 1);
    } else {
        int c = t;
        float i1 = g1[c]/sqrtf(v1[c]+1e-3f);
        s1[c] = i1; t1[c] = (c1b[c]-m1[c])*i1 + bb1[c];
        float i2 = g2[c]/sqrtf(v2[c]+1e-3f);
        s2[c] = i2; t2[c] = (c2b[c]-m2[c])*i2 + bb2[c];
    }
}

// imgf [img][ci=256][pix] fp32 -> pixel-major fp16 hi/lo [img*HW+pix][256]
__global__ void tsplit(const float* __restrict__ imgf,
                       _Float16* __restrict__ inH, _Float16* __restrict__ inL){
    __shared__ float tile[32][33];
    int img = blockIdx.z;
    int p0 = blockIdx.x*32, c0 = blockIdx.y*32;
    int tx = threadIdx.x & 31, ty = threadIdx.x >> 5;
#pragma unroll
    for (int k = 0; k < 4; ++k)
        tile[ty + 8*k][tx] = imgf[((size_t)(img*256 + c0 + ty + 8*k))*HW + p0 + tx];
    __syncthreads();
#pragma unroll
    for (int k = 0; k < 4; ++k){
        int pr = ty + 8*k, cc = tx;
        float v = tile[cc][pr];
        _Float16 h = (_Float16)v;
        size_t o = ((size_t)(img*HW + p0 + pr))*256 + c0 + cc;
        inH[o] = h; inL[o] = (_Float16)(v - (float)h);
    }
}

// ---------------- depth distribution (recomputed) + histogram/fill --------

struct DepthCtx { float metric, inv, mx, rs; };

__device__ __forceinline__ DepthCtx depth_ctx(float relv, float lsc, float shf, float lsg){
    DepthCtx c;
    float scale = expf(lsc);
    float sig   = fminf(fmaxf(expf(lsg), 0.1f), 20.f);
    c.inv = 1.f/sig;
    c.metric = fminf(fmaxf(scale*relv + shf, 0.5f), 150.f);
    float nb = fminf(fmaxf(rintf(c.metric), 1.f), 59.f);
    c.mx = -fabsf(c.metric - nb)*c.inv;
    float sum = 0.f;
    for (int d = 0; d < DD; ++d)
        sum += expf(-fabsf(c.metric - (float)(d+1))*c.inv - c.mx);
    c.rs = 1.f/sum;
    return c;
}

__global__ void count_kernel(const float* __restrict__ rel, const int* __restrict__ vids,
                             const float* __restrict__ lsc, const float* __restrict__ shf,
                             const float* __restrict__ lsg, int* __restrict__ counts){
    int g = blockIdx.x*256 + threadIdx.x;
    if (g >= NPIX) return;
    int bn = g/HW, p = g - bn*HW;
    DepthCtx c = depth_ctx(rel[g], lsc[0], shf[0], lsg[0]);
    for (int d = 0; d < DD; ++d){
        float w = expf(-fabsf(c.metric - (float)(d+1))*c.inv - c.mx)*c.rs;
        if (w >= WCUT) atomicAdd(&counts[vids[(bn*DD + d)*HW + p]], 1);
    }
}

__global__ void scan_kernel(const int* __restrict__ counts, int* __restrict__ offsets){
    __shared__ int part[1024];
    int t = threadIdx.x;
    int base = t*16;
    int s = 0;
    for (int i = 0; i < 16; ++i) s += counts[base+i];
    part[t] = s;
    __syncthreads();
    for (int off = 1; off < 1024; off <<= 1){
        int v = (t >= off) ? part[t-off] : 0;
        __syncthreads();
        part[t] += v;
        __syncthreads();
    }
    int run = (t == 0) ? 0 : part[t-1];
    for (int i = 0; i < 16; ++i){
        offsets[base+i] = run;
        run += counts[base+i];
    }
}

__global__ void fill_kernel(const float* __restrict__ rel, const int* __restrict__ vids,
                            const float* __restrict__ lsc, const float* __restrict__ shf,
                            const float* __restrict__ lsg,
                            const int* __restrict__ offsets, int* __restrict__ cursor,
                            int2* __restrict__ records){
    int g = blockIdx.x*256 + threadIdx.x;
    if (g >= NPIX) return;
    int bn = g/HW, p = g - bn*HW;
    DepthCtx c = depth_ctx(rel[g], lsc[0], shf[0], lsg[0]);
    for (int d = 0; d < DD; ++d){
        float w = expf(-fabsf(c.metric - (float)(d+1))*c.inv - c.mx)*c.rs;
        if (w >= WCUT){
            int v = vids[(bn*DD + d)*HW + p];
            int pos = atomicAdd(&cursor[v], 1);
            records[offsets[v] + pos] = make_int2(g, __float_as_int(w));
        }
    }
}

// ---------------- MFMA conv v3: A global->VGPR, B single-buf LDS ----------
// tile 64 px x 128 co, 128 thr = 2 waves, wave tile 64x64, BK=64.
// LDS 32KB: Bh[1024 slots]|Bl[1024 slots]; slot(row,oct) = row*8 + (oct^(row&7))
// (swizzle applied on the GLOBAL source; LDS dest linear -> rule-21 pattern)
template<int TAPS, bool BN_RELU, bool F16OUT, int COT>
__global__ __launch_bounds__(128,2) void conv_mfma(
    const _Float16* __restrict__ inH, const _Float16* __restrict__ inL,
    const _Float16* __restrict__ wHp, const _Float16* __restrict__ wLp,
    const float* __restrict__ scale, const float* __restrict__ bias,
    _Float16* __restrict__ outH, _Float16* __restrict__ outL,
    const _Float16* __restrict__ zp)
{
    __shared__ __align__(16) _Float16 lds[16384];   // Bh 0 | Bl 8192 (halfs)

    const int t    = threadIdx.x;      // 128
    const int wave = t >> 6;
    const int lane = t & 63;
    const int g    = lane >> 4;
    const int l15  = lane & 15;
    const int g0   = blockIdx.x*64;    // 2816%64==0: tiles never cross images
    const int img  = g0/HW;
    const int pbase= g0 - img*HW;
    const int n0   = blockIdx.y*128;
    const int imgbase = img*HW;
    const int NK   = TAPS*4;

    // B staging: 1024 slots of 16B per plane, 8 per thread per plane
    int bOff[8], bLo[8];
#pragma unroll
    for (int i = 0; i < 8; ++i){
        int s = i*128 + t;
        int row = s >> 3, oct = s & 7;
        bOff[i] = (n0 + row)*256 + (oct ^ (row & 7))*8;
        bLo[i]  = (i*128 + wave*64)*8;   // wave-uniform base; HW adds lane*16B
    }
    // A rows: 64 pixels shared by both waves
    int py[4], px[4];
#pragma unroll
    for (int f = 0; f < 4; ++f){
        int p = pbase + f*16 + l15;
        py[f] = p/88; px[f] = p - py[f]*88;
    }
    // B fragment rows: wave 0 -> co 0..63, wave 1 -> co 64..127
    int brow[4];
#pragma unroll
    for (int f = 0; f < 4; ++f) brow[f] = wave*64 + f*16 + l15;

    f32x4 acc[4][4];
#pragma unroll
    for (int i = 0; i < 4; ++i)
#pragma unroll
        for (int j = 0; j < 4; ++j) acc[i][j] = (f32x4){0.f,0.f,0.f,0.f};

    for (int kk = 0; kk < NK; ++kk){
        const int tap = kk >> 2, ci0 = (kk & 3) << 6;
        const int dy = (TAPS == 9) ? tap/3 - 1 : 0;
        const int dx = (TAPS == 9) ? tap - (tap/3)*3 - 1 : 0;

        __syncthreads();   // previous compute done reading LDS
        // stage B (both planes) via global_load_lds
        const _Float16* bH = wHp + (size_t)tap*COT*256 + ci0;
        const _Float16* bL = wLp + (size_t)tap*COT*256 + ci0;
#pragma unroll
        for (int i = 0; i < 8; ++i){
            glds16(bH + bOff[i], lds + bLo[i]);
            glds16(bL + bOff[i], lds + 8192 + bLo[i]);
        }
        // load A fragments global -> VGPR (L2-resident)
        half8 ah[4][2], al[4][2];
#pragma unroll
        for (int f = 0; f < 4; ++f){
            int yy = py[f] + dy, xx = px[f] + dx;
            bool valid = ((unsigned)yy < 32u) && ((unsigned)xx < 88u);
            int base = (imgbase + yy*88 + xx)*256 + ci0 + g*8;
            const _Float16* pH = valid ? inH + base : zp;
            const _Float16* pL = valid ? inL + base : zp;
            ah[f][0] = *(const half8*)(pH);
            ah[f][1] = *(const half8*)(pH + 32);
            al[f][0] = *(const half8*)(pL);
            al[f][1] = *(const half8*)(pL + 32);
        }
        __syncthreads();   // staging complete

#pragma unroll
        for (int ks = 0; ks < 2; ++ks){
            half8 bh[4], bl[4];
#pragma unroll
            for (int f = 0; f < 4; ++f){
                int eb = (brow[f]*8 + (((ks*4 + g) ^ (brow[f] & 7))))*8;
                bh[f] = *(const half8*)(lds + eb);
                bl[f] = *(const half8*)(lds + 8192 + eb);
            }
#pragma unroll
            for (int mi = 0; mi < 4; ++mi)
#pragma unroll
            for (int ni = 0; ni < 4; ++ni){
                acc[mi][ni] = __builtin_amdgcn_mfma_f32_16x16x32_f16(ah[mi][ks], bh[ni], acc[mi][ni], 0,0,0);
                acc[mi][ni] = __builtin_amdgcn_mfma_f32_16x16x32_f16(ah[mi][ks], bl[ni], acc[mi][ni], 0,0,0);
                acc[mi][ni] = __builtin_amdgcn_mfma_f32_16x16x32_f16(al[mi][ks], bh[ni], acc[mi][ni], 0,0,0);
            }
        }
    }

    // epilogue: C/D col(l15)=co, row=(lane>>4)*4+r = pixel
#pragma unroll
    for (int ni = 0; ni < 4; ++ni){
        int co = n0 + wave*64 + ni*16 + l15;
        float sc = BN_RELU ? scale[co] : 0.f;
        float bi = bias[co];
#pragma unroll
        for (int mi = 0; mi < 4; ++mi){
            f32x4 v = acc[mi][ni];
            int rb = g0 + mi*16 + g*4;
#pragma unroll
            for (int r = 0; r < 4; ++r){
                float y;
                if (BN_RELU) y = fmaxf(fmaf(v[r], sc, bi), 0.f);
                else         y = v[r] + bi;
                size_t o = (size_t)(rb + r)*COT + co;
                if constexpr (F16OUT){
                    outH[o] = (_Float16)y;
                } else {
                    _Float16 h = (_Float16)y;
                    outH[o] = h;
                    outL[o] = (_Float16)(y - (float)h);
                }
            }
        }
    }
}

// ---------------- atomic-free splat: gather per voxel (fp16 feat) ----------
// one wave per voxel, lane = 2 channels, 8-deep unrolled for MLP
__global__ __launch_bounds__(256,8) void gather_kernel(
    const int2* __restrict__ records, const int* __restrict__ offsets,
    const int* __restrict__ counts, const _Float16* __restrict__ feat16,
    float* __restrict__ bev_t){
    int v    = blockIdx.x*4 + (threadIdx.x >> 6);
    int lane = threadIdx.x & 63;
    int off = offsets[v], n = counts[v];
    float a0 = 0.f, a1 = 0.f;
    int i = 0;
    for (; i + 8 <= n; i += 8){
        int2 r[8];
#pragma unroll
        for (int j = 0; j < 8; ++j) r[j] = records[off+i+j];
        half2v f[8];
#pragma unroll
        for (int j = 0; j < 8; ++j)
            f[j] = *(const half2v*)(feat16 + (size_t)r[j].x*COUT + lane*2);
#pragma unroll
        for (int j = 0; j < 8; ++j){
            float w = __int_as_float(r[j].y);
            a0 = fmaf(w, (float)f[j][0], a0);
            a1 = fmaf(w, (float)f[j][1], a1);
        }
    }
    for (; i < n; ++i){
        int2 r = records[off+i];
        half2v f = *(const half2v*)(feat16 + (size_t)r.x*COUT + lane*2);
        float w = __int_as_float(r.y);
        a0 = fmaf(w, (float)f[0], a0); a1 = fmaf(w, (float)f[1], a1);
    }
    *(float2*)(bev_t + (size_t)v*COUT + lane*2) = make_float2(a0, a1);
}

// bev_t[v][c] -> out[c][v]
__global__ void transpose_out(const float* __restrict__ bev_t, float* __restrict__ out){
    __shared__ float tile[32][33];
    int v0 = blockIdx.x*32, c0 = blockIdx.y*32;
    int tx = threadIdx.x & 31, ty = threadIdx.x >> 5;
#pragma unroll
    for (int k = 0; k < 4; ++k)
        tile[ty + 8*k][tx] = bev_t[(size_t)(v0 + ty + 8*k)*COUT + c0 + tx];
    __syncthreads();
#pragma unroll
    for (int k = 0; k < 4; ++k)
        out[(size_t)(c0 + ty + 8*k)*NV + v0 + tx] = tile[tx][ty + 8*k];
}

// ---------------- launch ----------------

extern "C" void kernel_launch(void* const* d_in, const int* in_sizes, int n_in,
                              void* d_out, int out_size, void* d_ws, size_t ws_size,
                              hipStream_t stream){
    const float* rel  = (const float*)d_in[0];
    const float* imgf = (const float*)d_in[1];
    const int*   vids = (const int*)d_in[2];
    const float* lsc  = (const float*)d_in[3];
    const float* shf  = (const float*)d_in[4];
    const float* lsg  = (const float*)d_in[5];
    const float* w1   = (const float*)d_in[6];
    const float* b1   = (const float*)d_in[7];
    const float* g1   = (const float*)d_in[8];
    const float* bb1  = (const float*)d_in[9];
    const float* m1   = (const float*)d_in[10];
    const float* v1   = (const float*)d_in[11];
    const float* w2   = (const float*)d_in[12];
    const float* b2   = (const float*)d_in[13];
    const float* g2   = (const float*)d_in[14];
    const float* bb2  = (const float*)d_in[15];
    const float* m2   = (const float*)d_in[16];
    const float* v2   = (const float*)d_in[17];
    const float* w3   = (const float*)d_in[18];
    const float* b3   = (const float*)d_in[19];

    char* ws = (char*)d_ws;
    size_t o = 0;
    auto alloc = [&](size_t bytes)->char*{
        char* p = ws + o;
        o += (bytes + 255) & ~(size_t)255;
        return p;
    };
    int* counts  = (int*)alloc((size_t)(2*NV + 64)*4);   // counts | cursor | zpad(256B)
    int* cursor  = counts + NV;
    const _Float16* zpad16 = (const _Float16*)(counts + 2*NV);
    int* offsets = (int*)alloc((size_t)NV*4);

    _Float16* wT1H = (_Float16*)alloc((size_t)9*256*256*2);
    _Float16* wT1L = (_Float16*)alloc((size_t)9*256*256*2);
    _Float16* wT2H = (_Float16*)alloc((size_t)9*256*256*2);
    _Float16* wT2L = (_Float16*)alloc((size_t)9*256*256*2);
    _Float16* wT3H = (_Float16*)alloc((size_t)128*256*2);
    _Float16* wT3L = (_Float16*)alloc((size_t)128*256*2);
    float* s1 = (float*)alloc(256*4);
    float* t1 = (float*)alloc(256*4);
    float* s2 = (float*)alloc(256*4);
    float* t2 = (float*)alloc(256*4);

    _Float16* in0H = (_Float16*)alloc((size_t)NPIX*256*2);   // 8.65 MB
    _Float16* in0L = (_Float16*)alloc((size_t)NPIX*256*2);
    _Float16* h1H  = (_Float16*)alloc((size_t)NPIX*256*2);
    _Float16* h1L  = (_Float16*)alloc((size_t)NPIX*256*2);
    _Float16* feat16 = (_Float16*)alloc((size_t)NPIX*COUT*2);  // 4.3 MB
    float* bev_t   = (float*)alloc((size_t)NV*COUT*4);          // 8 MB
    // aliases: h2 planes reuse in0 (dead after conv1); records reuse h1L (dead after conv3)
    _Float16* h2H = in0H;
    _Float16* h2L = in0L;
    int2* records = (int2*)h1L;   // <= 8 MB needed, 8.65 MB available

    prep_kernel<<<4866,256,0,stream>>>(counts, 2*NV + 64,
        w1, wT1H, wT1L, w2, wT2H, wT2L, w3, wT3H, wT3L,
        b1,g1,bb1,m1,v1, b2,g2,bb2,m2,v2, s1,t1,s2,t2);
    tsplit<<<dim3(88,8,6),256,0,stream>>>(imgf, in0H, in0L);

    conv_mfma<9,true ,false,256><<<dim3(264,2),128,0,stream>>>(
        in0H, in0L, wT1H, wT1L, s1, t1, h1H, h1L, zpad16);
    conv_mfma<9,true ,false,256><<<dim3(264,2),128,0,stream>>>(
        h1H, h1L, wT2H, wT2L, s2, t2, h2H, h2L, zpad16);
    conv_mfma<1,false,true ,128><<<dim3(264,1),128,0,stream>>>(
        h2H, h2L, wT3H, wT3L, s1, b3, feat16, nullptr, zpad16);

    count_kernel<<<66,256,0,stream>>>(rel, vids, lsc, shf, lsg, counts);
    scan_kernel<<<1,1024,0,stream>>>(counts, offsets);
    fill_kernel<<<66,256,0,stream>>>(rel, vids, lsc, shf, lsg, offsets, cursor, records);

    gather_kernel<<<4096,256,0,stream>>>(records, offsets, counts, feat16, bev_t);
    transpose_out<<<dim3(512,4),256,0,stream>>>(bev_t, (float*)d_out);
}

// Round 7
// 237.864 us; speedup vs baseline: 2.2738x; 2.2738x over previous
//
#include <hip/hip_runtime.h>
#include <math.h>

#define HW   2816           // 32*88
#define IMGS 6
#define DD   59
#define NV   16384          // 128*128 BEV cells (B=1)
#define COUT 128
#define NPIX (IMGS*HW)      // 16896
#define WCUT 1e-5f
#define CAP  128            // records per voxel (Poisson(~42) after WCUT; overflow ~1e-28)

typedef _Float16 half8  __attribute__((ext_vector_type(8)));
typedef _Float16 half2v __attribute__((ext_vector_type(2)));
typedef float f32x4 __attribute__((ext_vector_type(4)));

__device__ __forceinline__ void glds16(const _Float16* g, const _Float16* l){
    __builtin_amdgcn_global_load_lds(
        (const __attribute__((address_space(1))) void*)g,
        (__attribute__((address_space(3))) void*)l, 16, 0, 0);
}

// ---------------- depth ctx ----------------

struct DepthCtx { float metric, inv, mx, rs; };

__device__ __forceinline__ DepthCtx depth_ctx(float relv, float lsc, float shf, float lsg){
    DepthCtx c;
    float scale = expf(lsc);
    float sig   = fminf(fmaxf(expf(lsg), 0.1f), 20.f);
    c.inv = 1.f/sig;
    c.metric = fminf(fmaxf(scale*relv + shf, 0.5f), 150.f);
    float nb = fminf(fmaxf(rintf(c.metric), 1.f), 59.f);
    c.mx = -fabsf(c.metric - nb)*c.inv;
    float sum = 0.f;
    for (int d = 0; d < DD; ++d)
        sum += expf(-fabsf(c.metric - (float)(d+1))*c.inv - c.mx);
    c.rs = 1.f/sum;
    return c;
}

// ---------------- fused prep: zero | wsplit x3 | bn | dparams | tsplit -----

__device__ __forceinline__ void wsplit_body(const float* __restrict__ w,
                                            _Float16* __restrict__ wh,
                                            int idx, int CO, int CI, int KK){
    if (idx >= CO*CI*KK) return;
    int co  = idx/(CI*KK);
    int r   = idx - co*CI*KK;
    int ci  = r/KK;
    int tap = r - ci*KK;
    wh[((size_t)tap*CO + co)*CI + ci] = (_Float16)w[idx];
}

// block ranges: [0,65) zero | [65,2369) w1 | [2369,4673) w2 | [4673,4801) w3
//               4801 bn | [4802,4868) dparams | [4868,9092) tsplit
__global__ void prep_kernel(int* __restrict__ cursor,
                            const float* __restrict__ w1, _Float16* __restrict__ wh1,
                            const float* __restrict__ w2, _Float16* __restrict__ wh2,
                            const float* __restrict__ w3, _Float16* __restrict__ wh3,
                            const float* __restrict__ c1b, const float* __restrict__ g1,
                            const float* __restrict__ bb1, const float* __restrict__ m1,
                            const float* __restrict__ v1,
                            const float* __restrict__ c2b, const float* __restrict__ g2,
                            const float* __restrict__ bb2, const float* __restrict__ m2,
                            const float* __restrict__ v2,
                            float* __restrict__ s1, float* __restrict__ t1,
                            float* __restrict__ s2, float* __restrict__ t2,
                            const float* __restrict__ rel, const float* __restrict__ lsc,
                            const float* __restrict__ shf, const float* __restrict__ lsg,
                            float4* __restrict__ dparams,
                            const float* __restrict__ imgf, _Float16* __restrict__ inH){
    __shared__ float tile[32][33];
    int b = blockIdx.x, t = threadIdx.x;
    if (b < 65){
        int i = b*256 + t;
        if (i < NV + 64) cursor[i] = 0;
    } else if (b < 2369){
        wsplit_body(w1, wh1, (b-65)*256 + t, 256, 256, 9);
    } else if (b < 4673){
        wsplit_body(w2, wh2, (b-2369)*256 + t, 256, 256, 9);
    } else if (b < 4801){
        wsplit_body(w3, wh3, (b-4673)*256 + t, 128, 256, 1);
    } else if (b == 4801){
        int c = t;
        float i1 = g1[c]/sqrtf(v1[c]+1e-3f);
        s1[c] = i1; t1[c] = (c1b[c]-m1[c])*i1 + bb1[c];
        float i2 = g2[c]/sqrtf(v2[c]+1e-3f);
        s2[c] = i2; t2[c] = (c2b[c]-m2[c])*i2 + bb2[c];
    } else if (b < 4868){
        int g = (b-4802)*256 + t;
        if (g < NPIX){
            DepthCtx c = depth_ctx(rel[g], lsc[0], shf[0], lsg[0]);
            dparams[g] = make_float4(c.metric, c.inv, c.mx, c.rs);
        }
    } else {
        int bb = b - 4868;                 // tsplit: 6 imgs x 88 p-tiles x 8 c-tiles
        int img = bb/704, rem = bb - img*704;
        int p0 = (rem % 88)*32, c0 = (rem/88)*32;
        int tx = t & 31, ty = t >> 5;
#pragma unroll
        for (int k = 0; k < 4; ++k)
            tile[ty + 8*k][tx] = imgf[((size_t)(img*256 + c0 + ty + 8*k))*HW + p0 + tx];
        __syncthreads();
#pragma unroll
        for (int k = 0; k < 4; ++k)
            inH[((size_t)(img*HW + p0 + ty + 8*k))*256 + c0 + tx] = (_Float16)tile[tx][ty + 8*k];
    }
}

// ---------------- MFMA conv (1-term fp16, R3-proven structure) -------------
// tile 64 px x 128 co, BK=64, 256 thr = 4 waves (2x2), wave tile 32x64.
// LDS 24KB: As 64x64 halfs (8KB) | Bs 128x64 halfs (16KB)
// 16B-slot swizzle: slot(row,oct) = row*8 + (oct ^ (row&7)); swizzle applied
// on the GLOBAL source, LDS dest linear (rule-21 both-sides pattern).
template<int TAPS, bool BN_RELU, int COT>
__global__ __launch_bounds__(256,4) void conv_mfma(
    const _Float16* __restrict__ in,   // [NPIX][256]
    const _Float16* __restrict__ wT,   // [TAPS][COT][256]
    const float* __restrict__ scale, const float* __restrict__ bias,
    _Float16* __restrict__ out,        // [NPIX][COT]
    const _Float16* __restrict__ zp)
{
    __shared__ __align__(16) _Float16 As[4096];
    __shared__ __align__(16) _Float16 Bs[8192];

    const int t    = threadIdx.x;
    const int wave = t >> 6;
    const int lane = t & 63;
    const int g    = lane >> 4;
    const int l15  = lane & 15;
    const int wr   = wave >> 1, wc = wave & 1;
    const int g0   = blockIdx.x*64;    // 2816%64==0: tiles never cross images
    const int img  = g0/HW;
    const int pbase= g0 - img*HW;
    const int n0   = blockIdx.y*128;
    const int imgbase = img*HW;
    const int NK   = TAPS*4;

    // A staging: 512 slots of 16B, 2 per thread
    int aPy[2], aPx[2], aOct[2], aLo[2];
#pragma unroll
    for (int i = 0; i < 2; ++i){
        int s = i*256 + t;
        int row = s >> 3;
        aOct[i] = ((s & 7) ^ (row & 7))*8;
        int p = pbase + row;
        aPy[i] = p/88; aPx[i] = p - aPy[i]*88;
        aLo[i] = (i*256 + wave*64)*8;      // wave-uniform; HW adds lane*16B
    }
    // B staging: 1024 slots, 4 per thread
    int bOff[4], bLo[4];
#pragma unroll
    for (int i = 0; i < 4; ++i){
        int s = i*256 + t;
        int row = s >> 3;
        bOff[i] = (n0 + row)*256 + ((s & 7) ^ (row & 7))*8;
        bLo[i]  = (i*256 + wave*64)*8;
    }
    int arow[2], brow[4];
#pragma unroll
    for (int f = 0; f < 2; ++f) arow[f] = wr*32 + f*16 + l15;
#pragma unroll
    for (int f = 0; f < 4; ++f) brow[f] = wc*64 + f*16 + l15;

    f32x4 acc[2][4];
#pragma unroll
    for (int i = 0; i < 2; ++i)
#pragma unroll
        for (int j = 0; j < 4; ++j) acc[i][j] = (f32x4){0.f,0.f,0.f,0.f};

    for (int kk = 0; kk < NK; ++kk){
        const int tap = kk >> 2, ci0 = (kk & 3) << 6;
        const int dy = (TAPS == 9) ? tap/3 - 1 : 0;
        const int dx = (TAPS == 9) ? tap - (tap/3)*3 - 1 : 0;

        __syncthreads();   // all waves done reading LDS
#pragma unroll
        for (int i = 0; i < 2; ++i){
            int yy = aPy[i] + dy, xx = aPx[i] + dx;
            bool valid = ((unsigned)yy < 32u) && ((unsigned)xx < 88u);
            const _Float16* src = valid
                ? in + (size_t)(imgbase + yy*88 + xx)*256 + ci0 + aOct[i] : zp;
            glds16(src, As + aLo[i]);
        }
        const _Float16* wb = wT + (size_t)tap*COT*256 + ci0;
#pragma unroll
        for (int i = 0; i < 4; ++i)
            glds16(wb + bOff[i], Bs + bLo[i]);
        __syncthreads();   // staging complete (vmcnt drained at barrier)

#pragma unroll
        for (int ks = 0; ks < 2; ++ks){
            half8 a[2], bf[4];
#pragma unroll
            for (int f = 0; f < 2; ++f)
                a[f] = *(const half8*)(As + (arow[f]*8 + (((ks*4 + g) ^ (arow[f] & 7))))*8);
#pragma unroll
            for (int f = 0; f < 4; ++f)
                bf[f] = *(const half8*)(Bs + (brow[f]*8 + (((ks*4 + g) ^ (brow[f] & 7))))*8);
#pragma unroll
            for (int mi = 0; mi < 2; ++mi)
#pragma unroll
            for (int ni = 0; ni < 4; ++ni)
                acc[mi][ni] = __builtin_amdgcn_mfma_f32_16x16x32_f16(a[mi], bf[ni], acc[mi][ni], 0,0,0);
        }
    }

    // epilogue: C/D col(l15)=co, row=(lane>>4)*4+r = pixel
#pragma unroll
    for (int ni = 0; ni < 4; ++ni){
        int co = n0 + wc*64 + ni*16 + l15;
        float sc = BN_RELU ? scale[co] : 0.f;
        float bi = bias[co];
#pragma unroll
        for (int mi = 0; mi < 2; ++mi){
            f32x4 v = acc[mi][ni];
            int rb = g0 + wr*32 + mi*16 + g*4;
#pragma unroll
            for (int r = 0; r < 4; ++r){
                float y;
                if (BN_RELU) y = fmaxf(fmaf(v[r], sc, bi), 0.f);
                else         y = v[r] + bi;
                out[(size_t)(rb + r)*COT + co] = (_Float16)y;
            }
        }
    }
}

// ---------------- capacity-bucket fill (no count/scan) ---------------------
// 1 thread per (pixel, depth-bin); coalesced vids; cursor doubles as count
__global__ void fill_kernel(const float4* __restrict__ dparams,
                            const int* __restrict__ vids,
                            int* __restrict__ cursor, int2* __restrict__ records){
    int tid = blockIdx.x*256 + threadIdx.x;
    if (tid >= NPIX*DD) return;
    int d  = tid/NPIX;
    int pp = tid - d*NPIX;
    int bn = pp/HW;
    int p  = pp - bn*HW;
    float4 c = dparams[pp];
    float w = expf(-fabsf(c.x - (float)(d+1))*c.y - c.z)*c.w;
    if (w >= WCUT){
        int v = vids[(bn*DD + d)*HW + p];
        int pos = atomicAdd(&cursor[v], 1);
        if (pos < CAP) records[v*CAP + pos] = make_int2(pp, __float_as_int(w));
    }
}

// ---------------- atomic-free splat: gather per voxel (fp16 feat) ----------
__global__ __launch_bounds__(256,8) void gather_kernel(
    const int2* __restrict__ records, const int* __restrict__ cursor,
    const _Float16* __restrict__ feat16, float* __restrict__ bev_t){
    int v    = blockIdx.x*4 + (threadIdx.x >> 6);
    int lane = threadIdx.x & 63;
    int n = min(cursor[v], CAP);
    const int2* rec = records + v*CAP;
    float a0 = 0.f, a1 = 0.f;
    int i = 0;
    for (; i + 8 <= n; i += 8){
        int2 r[8];
#pragma unroll
        for (int j = 0; j < 8; ++j) r[j] = rec[i+j];
        half2v f[8];
#pragma unroll
        for (int j = 0; j < 8; ++j)
            f[j] = *(const half2v*)(feat16 + (size_t)r[j].x*COUT + lane*2);
#pragma unroll
        for (int j = 0; j < 8; ++j){
            float w = __int_as_float(r[j].y);
            a0 = fmaf(w, (float)f[j][0], a0);
            a1 = fmaf(w, (float)f[j][1], a1);
        }
    }
    for (; i < n; ++i){
        int2 r = rec[i];
        half2v f = *(const half2v*)(feat16 + (size_t)r.x*COUT + lane*2);
        float w = __int_as_float(r.y);
        a0 = fmaf(w, (float)f[0], a0); a1 = fmaf(w, (float)f[1], a1);
    }
    *(float2*)(bev_t + (size_t)v*COUT + lane*2) = make_float2(a0, a1);
}

// bev_t[v][c] -> out[c][v]
__global__ void transpose_out(const float* __restrict__ bev_t, float* __restrict__ out){
    __shared__ float tile[32][33];
    int v0 = blockIdx.x*32, c0 = blockIdx.y*32;
    int tx = threadIdx.x & 31, ty = threadIdx.x >> 5;
#pragma unroll
    for (int k = 0; k < 4; ++k)
        tile[ty + 8*k][tx] = bev_t[(size_t)(v0 + ty + 8*k)*COUT + c0 + tx];
    __syncthreads();
#pragma unroll
    for (int k = 0; k < 4; ++k)
        out[(size_t)(c0 + ty + 8*k)*NV + v0 + tx] = tile[tx][ty + 8*k];
}

// ---------------- launch ----------------

extern "C" void kernel_launch(void* const* d_in, const int* in_sizes, int n_in,
                              void* d_out, int out_size, void* d_ws, size_t ws_size,
                              hipStream_t stream){
    const float* rel  = (const float*)d_in[0];
    const float* imgf = (const float*)d_in[1];
    const int*   vids = (const int*)d_in[2];
    const float* lsc  = (const float*)d_in[3];
    const float* shf  = (const float*)d_in[4];
    const float* lsg  = (const float*)d_in[5];
    const float* w1   = (const float*)d_in[6];
    const float* b1   = (const float*)d_in[7];
    const float* g1   = (const float*)d_in[8];
    const float* bb1  = (const float*)d_in[9];
    const float* m1   = (const float*)d_in[10];
    const float* v1   = (const float*)d_in[11];
    const float* w2   = (const float*)d_in[12];
    const float* b2   = (const float*)d_in[13];
    const float* g2   = (const float*)d_in[14];
    const float* bb2  = (const float*)d_in[15];
    const float* m2   = (const float*)d_in[16];
    const float* v2   = (const float*)d_in[17];
    const float* w3   = (const float*)d_in[18];
    const float* b3   = (const float*)d_in[19];

    char* ws = (char*)d_ws;
    size_t o = 0;
    auto alloc = [&](size_t bytes)->char*{
        char* p = ws + o;
        o += (bytes + 255) & ~(size_t)255;
        return p;
    };
    int* cursor = (int*)alloc((size_t)(NV + 64)*4);      // cursor | zpad (zeroed by prep)
    const _Float16* zpad16 = (const _Float16*)(cursor + NV);
    float4* dparams = (float4*)alloc((size_t)NPIX*16);

    _Float16* wT1 = (_Float16*)alloc((size_t)9*256*256*2);
    _Float16* wT2 = (_Float16*)alloc((size_t)9*256*256*2);
    _Float16* wT3 = (_Float16*)alloc((size_t)128*256*2);
    float* s1 = (float*)alloc(256*4);
    float* t1 = (float*)alloc(256*4);
    float* s2 = (float*)alloc(256*4);
    float* t2 = (float*)alloc(256*4);

    _Float16* in0 = (_Float16*)alloc((size_t)NPIX*256*2);     // 8.65 MB
    _Float16* h1  = (_Float16*)alloc((size_t)NPIX*256*2);     // 8.65 MB
    _Float16* feat16 = (_Float16*)alloc((size_t)NPIX*COUT*2); // 4.3 MB
    float* bev_t  = (float*)alloc((size_t)NV*COUT*4);         // 8 MB
    int2* records = (int2*)alloc((size_t)NV*CAP*8);           // 16 MB
    _Float16* h2 = in0;   // in0 dead after conv1

    prep_kernel<<<9092,256,0,stream>>>(cursor,
        w1, wT1, w2, wT2, w3, wT3,
        b1,g1,bb1,m1,v1, b2,g2,bb2,m2,v2, s1,t1,s2,t2,
        rel, lsc, shf, lsg, dparams, imgf, in0);

    conv_mfma<9,true ,256><<<dim3(264,2),256,0,stream>>>(in0, wT1, s1, t1, h1, zpad16);
    conv_mfma<9,true ,256><<<dim3(264,2),256,0,stream>>>(h1,  wT2, s2, t2, h2, zpad16);
    conv_mfma<1,false,128><<<dim3(264,1),256,0,stream>>>(h2,  wT3, s1, b3, feat16, zpad16);

    fill_kernel<<<3894,256,0,stream>>>(dparams, vids, cursor, records);
    gather_kernel<<<4096,256,0,stream>>>(records, cursor, feat16, bev_t);
    transpose_out<<<dim3(512,4),256,0,stream>>>(bev_t, (float*)d_out);
}

// Round 9
// 236.658 us; speedup vs baseline: 2.2853x; 1.0051x over previous
//
#include <hip/hip_runtime.h>
#include <math.h>

#define HW   2816           // 32*88
#define IMGS 6
#define DD   59
#define NV   16384          // 128*128 BEV cells (B=1)
#define COUT 128
#define NPIX (IMGS*HW)      // 16896
#define WCUT 1e-5f
#define CAP  128            // records per voxel (Poisson(~42) after WCUT; overflow ~1e-28)
#define NCONV1 528          // conv1 blocks in fused conv1+fill dispatch
#define NFILL  3894         // fill blocks  (NPIX*DD/256 = 3894 exactly)

typedef _Float16 half8  __attribute__((ext_vector_type(8)));
typedef _Float16 half2v __attribute__((ext_vector_type(2)));
typedef float f32x4 __attribute__((ext_vector_type(4)));

__device__ __forceinline__ void glds16(const _Float16* g, const _Float16* l){
    __builtin_amdgcn_global_load_lds(
        (const __attribute__((address_space(1))) void*)g,
        (__attribute__((address_space(3))) void*)l, 16, 0, 0);
}

// ---------------- depth ctx ----------------

struct DepthCtx { float metric, inv, mx, rs; };

__device__ __forceinline__ DepthCtx depth_ctx(float relv, float lsc, float shf, float lsg){
    DepthCtx c;
    float scale = expf(lsc);
    float sig   = fminf(fmaxf(expf(lsg), 0.1f), 20.f);
    c.inv = 1.f/sig;
    c.metric = fminf(fmaxf(scale*relv + shf, 0.5f), 150.f);
    float nb = fminf(fmaxf(rintf(c.metric), 1.f), 59.f);
    c.mx = -fabsf(c.metric - nb)*c.inv;
    float sum = 0.f;
    for (int d = 0; d < DD; ++d)
        sum += expf(-fabsf(c.metric - (float)(d+1))*c.inv - c.mx);
    c.rs = 1.f/sum;
    return c;
}

// ---------------- fused prep: zero | wsplit x3 | bn | dparams | tsplit -----
// wsplit: thread = OUTPUT element (coalesced 2B writes); reads strided (L2-cached)

__device__ __forceinline__ void wsplit_body(const float* __restrict__ w,
                                            _Float16* __restrict__ wh,
                                            int o, int CO, int CI, int KK){
    if (o >= CO*CI*KK) return;
    int tap = o/(CO*CI);
    int r   = o - tap*CO*CI;
    int co  = r/CI;
    int ci  = r - co*CI;
    wh[o] = (_Float16)w[(co*CI + ci)*KK + tap];
}

// block ranges: [0,65) zero | [65,2369) w1 | [2369,4673) w2 | [4673,4801) w3
//               4801 bn | [4802,4868) dparams | [4868,9092) tsplit
__global__ void prep_kernel(int* __restrict__ cursor,
                            const float* __restrict__ w1, _Float16* __restrict__ wh1,
                            const float* __restrict__ w2, _Float16* __restrict__ wh2,
                            const float* __restrict__ w3, _Float16* __restrict__ wh3,
                            const float* __restrict__ c1b, const float* __restrict__ g1,
                            const float* __restrict__ bb1, const float* __restrict__ m1,
                            const float* __restrict__ v1,
                            const float* __restrict__ c2b, const float* __restrict__ g2,
                            const float* __restrict__ bb2, const float* __restrict__ m2,
                            const float* __restrict__ v2,
                            float* __restrict__ s1, float* __restrict__ t1,
                            float* __restrict__ s2, float* __restrict__ t2,
                            const float* __restrict__ rel, const float* __restrict__ lsc,
                            const float* __restrict__ shf, const float* __restrict__ lsg,
                            float4* __restrict__ dparams,
                            const float* __restrict__ imgf, _Float16* __restrict__ inH){
    __shared__ float tile[32][33];
    int b = blockIdx.x, t = threadIdx.x;
    if (b < 65){
        int i = b*256 + t;
        if (i < NV + 64) cursor[i] = 0;
    } else if (b < 2369){
        wsplit_body(w1, wh1, (b-65)*256 + t, 256, 256, 9);
    } else if (b < 4673){
        wsplit_body(w2, wh2, (b-2369)*256 + t, 256, 256, 9);
    } else if (b < 4801){
        wsplit_body(w3, wh3, (b-4673)*256 + t, 128, 256, 1);
    } else if (b == 4801){
        int c = t;
        float i1 = g1[c]/sqrtf(v1[c]+1e-3f);
        s1[c] = i1; t1[c] = (c1b[c]-m1[c])*i1 + bb1[c];
        float i2 = g2[c]/sqrtf(v2[c]+1e-3f);
        s2[c] = i2; t2[c] = (c2b[c]-m2[c])*i2 + bb2[c];
    } else if (b < 4868){
        int g = (b-4802)*256 + t;
        if (g < NPIX){
            DepthCtx c = depth_ctx(rel[g], lsc[0], shf[0], lsg[0]);
            dparams[g] = make_float4(c.metric, c.inv, c.mx, c.rs);
        }
    } else {
        int bb = b - 4868;                 // tsplit: 6 imgs x 88 p-tiles x 8 c-tiles
        int img = bb/704, rem = bb - img*704;
        int p0 = (rem % 88)*32, c0 = (rem/88)*32;
        int tx = t & 31, ty = t >> 5;
#pragma unroll
        for (int k = 0; k < 4; ++k)
            tile[ty + 8*k][tx] = imgf[((size_t)(img*256 + c0 + ty + 8*k))*HW + p0 + tx];
        __syncthreads();
#pragma unroll
        for (int k = 0; k < 4; ++k)
            inH[((size_t)(img*HW + p0 + ty + 8*k))*256 + c0 + tx] = (_Float16)tile[tx][ty + 8*k];
    }
}

// ---------------- MFMA conv body (1-term fp16, R3/R7-proven structure) -----
// tile 64 px x 128 co, BK=64, 256 thr = 4 waves (2x2), wave tile 32x64.
// LDS 24KB: As 64x64 halfs (8KB) | Bs 128x64 halfs (16KB)
// 16B-slot swizzle: slot(row,oct) = row*8 + (oct ^ (row&7)); swizzle applied
// on the GLOBAL source, LDS dest linear (rule-21 both-sides pattern).
template<int TAPS, bool BN_RELU, int COT>
__device__ __forceinline__ void conv_body(int bx, int by,
    const _Float16* __restrict__ in,   // [NPIX][256]
    const _Float16* __restrict__ wT,   // [TAPS][COT][256]
    const float* __restrict__ scale, const float* __restrict__ bias,
    _Float16* __restrict__ out,        // [NPIX][COT]
    const _Float16* __restrict__ zp)
{
    __shared__ __align__(16) _Float16 As[4096];
    __shared__ __align__(16) _Float16 Bs[8192];

    const int t    = threadIdx.x;
    const int wave = t >> 6;
    const int lane = t & 63;
    const int g    = lane >> 4;
    const int l15  = lane & 15;
    const int wr   = wave >> 1, wc = wave & 1;
    const int g0   = bx*64;            // 2816%64==0: tiles never cross images
    const int img  = g0/HW;
    const int pbase= g0 - img*HW;
    const int n0   = by*128;
    const int imgbase = img*HW;
    const int NK   = TAPS*4;

    // A staging: 512 slots of 16B, 2 per thread
    int aPy[2], aPx[2], aOct[2], aLo[2];
#pragma unroll
    for (int i = 0; i < 2; ++i){
        int s = i*256 + t;
        int row = s >> 3;
        aOct[i] = ((s & 7) ^ (row & 7))*8;
        int p = pbase + row;
        aPy[i] = p/88; aPx[i] = p - aPy[i]*88;
        aLo[i] = (i*256 + wave*64)*8;      // wave-uniform; HW adds lane*16B
    }
    // B staging: 1024 slots, 4 per thread
    int bOff[4], bLo[4];
#pragma unroll
    for (int i = 0; i < 4; ++i){
        int s = i*256 + t;
        int row = s >> 3;
        bOff[i] = (n0 + row)*256 + ((s & 7) ^ (row & 7))*8;
        bLo[i]  = (i*256 + wave*64)*8;
    }
    int arow[2], brow[4];
#pragma unroll
    for (int f = 0; f < 2; ++f) arow[f] = wr*32 + f*16 + l15;
#pragma unroll
    for (int f = 0; f < 4; ++f) brow[f] = wc*64 + f*16 + l15;

    f32x4 acc[2][4];
#pragma unroll
    for (int i = 0; i < 2; ++i)
#pragma unroll
        for (int j = 0; j < 4; ++j) acc[i][j] = (f32x4){0.f,0.f,0.f,0.f};

    for (int kk = 0; kk < NK; ++kk){
        const int tap = kk >> 2, ci0 = (kk & 3) << 6;
        const int dy = (TAPS == 9) ? tap/3 - 1 : 0;
        const int dx = (TAPS == 9) ? tap - (tap/3)*3 - 1 : 0;

        __syncthreads();   // all waves done reading LDS
#pragma unroll
        for (int i = 0; i < 2; ++i){
            int yy = aPy[i] + dy, xx = aPx[i] + dx;
            bool valid = ((unsigned)yy < 32u) && ((unsigned)xx < 88u);
            const _Float16* src = valid
                ? in + (size_t)(imgbase + yy*88 + xx)*256 + ci0 + aOct[i] : zp;
            glds16(src, As + aLo[i]);
        }
        const _Float16* wb = wT + (size_t)tap*COT*256 + ci0;
#pragma unroll
        for (int i = 0; i < 4; ++i)
            glds16(wb + bOff[i], Bs + bLo[i]);
        __syncthreads();   // staging complete (vmcnt drained at barrier)

#pragma unroll
        for (int ks = 0; ks < 2; ++ks){
            half8 a[2], bf[4];
#pragma unroll
            for (int f = 0; f < 2; ++f)
                a[f] = *(const half8*)(As + (arow[f]*8 + (((ks*4 + g) ^ (arow[f] & 7))))*8);
#pragma unroll
            for (int f = 0; f < 4; ++f)
                bf[f] = *(const half8*)(Bs + (brow[f]*8 + (((ks*4 + g) ^ (brow[f] & 7))))*8);
#pragma unroll
            for (int mi = 0; mi < 2; ++mi)
#pragma unroll
            for (int ni = 0; ni < 4; ++ni)
                acc[mi][ni] = __builtin_amdgcn_mfma_f32_16x16x32_f16(a[mi], bf[ni], acc[mi][ni], 0,0,0);
        }
    }

    // epilogue: C/D col(l15)=co, row=(lane>>4)*4+r = pixel
#pragma unroll
    for (int ni = 0; ni < 4; ++ni){
        int co = n0 + wc*64 + ni*16 + l15;
        float sc = BN_RELU ? scale[co] : 0.f;
        float bi = bias[co];
#pragma unroll
        for (int mi = 0; mi < 2; ++mi){
            f32x4 v = acc[mi][ni];
            int rb = g0 + wr*32 + mi*16 + g*4;
#pragma unroll
            for (int r = 0; r < 4; ++r){
                float y;
                if (BN_RELU) y = fmaxf(fmaf(v[r], sc, bi), 0.f);
                else         y = v[r] + bi;
                out[(size_t)(rb + r)*COT + co] = (_Float16)y;
            }
        }
    }
}

// capacity-bucket fill body: 1 thread per (pixel, depth-bin)
__device__ __forceinline__ void fill_body(int bb, int t,
    const float4* __restrict__ dparams, const int* __restrict__ vids,
    int* __restrict__ cursor, int2* __restrict__ records){
    int tid = bb*256 + t;
    if (tid >= NPIX*DD) return;
    int d  = tid/NPIX;
    int pp = tid - d*NPIX;
    int bn = pp/HW;
    int p  = pp - bn*HW;
    float4 c = dparams[pp];
    float w = expf(-fabsf(c.x - (float)(d+1))*c.y - c.z)*c.w;
    if (w >= WCUT){
        int v = vids[(bn*DD + d)*HW + p];
        int pos = atomicAdd(&cursor[v], 1);
        if (pos < CAP) records[v*CAP + pos] = make_int2(pp, __float_as_int(w));
    }
}

// standalone conv (conv2 / conv3)
template<int TAPS, bool BN_RELU, int COT>
__global__ __launch_bounds__(256,6) void conv_mfma(
    const _Float16* __restrict__ in, const _Float16* __restrict__ wT,
    const float* __restrict__ scale, const float* __restrict__ bias,
    _Float16* __restrict__ out, const _Float16* __restrict__ zp){
    conv_body<TAPS,BN_RELU,COT>(blockIdx.x, blockIdx.y, in, wT, scale, bias, out, zp);
}

// fused conv1 + fill: conv blocks [0,528), fill blocks [528, 528+3894)
__global__ __launch_bounds__(256,6) void conv1_fill_kernel(
    const _Float16* __restrict__ in, const _Float16* __restrict__ wT,
    const float* __restrict__ scale, const float* __restrict__ bias,
    _Float16* __restrict__ out, const _Float16* __restrict__ zp,
    const float4* __restrict__ dparams, const int* __restrict__ vids,
    int* __restrict__ cursor, int2* __restrict__ records){
    int b = blockIdx.x;
    if (b < NCONV1){
        conv_body<9,true,256>(b % 264, b / 264, in, wT, scale, bias, out, zp);
    } else {
        fill_body(b - NCONV1, threadIdx.x, dparams, vids, cursor, records);
    }
}

// ---------------- atomic-free splat: gather per voxel (fp16 feat) ----------
__global__ __launch_bounds__(256,8) void gather_kernel(
    const int2* __restrict__ records, const int* __restrict__ cursor,
    const _Float16* __restrict__ feat16, float* __restrict__ bev_t){
    int v    = blockIdx.x*4 + (threadIdx.x >> 6);
    int lane = threadIdx.x & 63;
    int n = min(cursor[v], CAP);
    const int2* rec = records + v*CAP;
    float a0 = 0.f, a1 = 0.f;
    int i = 0;
    for (; i + 8 <= n; i += 8){
        int2 r[8];
#pragma unroll
        for (int j = 0; j < 8; ++j) r[j] = rec[i+j];
        half2v f[8];
#pragma unroll
        for (int j = 0; j < 8; ++j)
            f[j] = *(const half2v*)(feat16 + (size_t)r[j].x*COUT + lane*2);
#pragma unroll
        for (int j = 0; j < 8; ++j){
            float w = __int_as_float(r[j].y);
            a0 = fmaf(w, (float)f[j][0], a0);
            a1 = fmaf(w, (float)f[j][1], a1);
        }
    }
    for (; i < n; ++i){
        int2 r = rec[i];
        half2v f = *(const half2v*)(feat16 + (size_t)r.x*COUT + lane*2);
        float w = __int_as_float(r.y);
        a0 = fmaf(w, (float)f[0], a0); a1 = fmaf(w, (float)f[1], a1);
    }
    *(float2*)(bev_t + (size_t)v*COUT + lane*2) = make_float2(a0, a1);
}

// bev_t[v][c] -> out[c][v]
__global__ void transpose_out(const float* __restrict__ bev_t, float* __restrict__ out){
    __shared__ float tile[32][33];
    int v0 = blockIdx.x*32, c0 = blockIdx.y*32;
    int tx = threadIdx.x & 31, ty = threadIdx.x >> 5;
#pragma unroll
    for (int k = 0; k < 4; ++k)
        tile[ty + 8*k][tx] = bev_t[(size_t)(v0 + ty + 8*k)*COUT + c0 + tx];
    __syncthreads();
#pragma unroll
    for (int k = 0; k < 4; ++k)
        out[(size_t)(c0 + ty + 8*k)*NV + v0 + tx] = tile[tx][ty + 8*k];
}

// ---------------- launch ----------------

extern "C" void kernel_launch(void* const* d_in, const int* in_sizes, int n_in,
                              void* d_out, int out_size, void* d_ws, size_t ws_size,
                              hipStream_t stream){
    const float* rel  = (const float*)d_in[0];
    const float* imgf = (const float*)d_in[1];
    const int*   vids = (const int*)d_in[2];
    const float* lsc  = (const float*)d_in[3];
    const float* shf  = (const float*)d_in[4];
    const float* lsg  = (const float*)d_in[5];
    const float* w1   = (const float*)d_in[6];
    const float* b1   = (const float*)d_in[7];
    const float* g1   = (const float*)d_in[8];
    const float* bb1  = (const float*)d_in[9];
    const float* m1   = (const float*)d_in[10];
    const float* v1   = (const float*)d_in[11];
    const float* w2   = (const float*)d_in[12];
    const float* b2   = (const float*)d_in[13];
    const float* g2   = (const float*)d_in[14];
    const float* bb2  = (const float*)d_in[15];
    const float* m2   = (const float*)d_in[16];
    const float* v2   = (const float*)d_in[17];
    const float* w3   = (const float*)d_in[18];
    const float* b3   = (const float*)d_in[19];

    char* ws = (char*)d_ws;
    size_t o = 0;
    auto alloc = [&](size_t bytes)->char*{
        char* p = ws + o;
        o += (bytes + 255) & ~(size_t)255;
        return p;
    };
    int* cursor = (int*)alloc((size_t)(NV + 64)*4);      // cursor | zpad (zeroed by prep)
    const _Float16* zpad16 = (const _Float16*)(cursor + NV);
    float4* dparams = (float4*)alloc((size_t)NPIX*16);

    _Float16* wT1 = (_Float16*)alloc((size_t)9*256*256*2);
    _Float16* wT2 = (_Float16*)alloc((size_t)9*256*256*2);
    _Float16* wT3 = (_Float16*)alloc((size_t)128*256*2);
    float* s1 = (float*)alloc(256*4);
    float* t1 = (float*)alloc(256*4);
    float* s2 = (float*)alloc(256*4);
    float* t2 = (float*)alloc(256*4);

    _Float16* in0 = (_Float16*)alloc((size_t)NPIX*256*2);     // 8.65 MB
    _Float16* h1  = (_Float16*)alloc((size_t)NPIX*256*2);     // 8.65 MB
    _Float16* feat16 = (_Float16*)alloc((size_t)NPIX*COUT*2); // 4.3 MB
    float* bev_t  = (float*)alloc((size_t)NV*COUT*4);         // 8 MB
    int2* records = (int2*)alloc((size_t)NV*CAP*8);           // 16 MB
    _Float16* h2 = in0;   // in0 dead after conv1

    prep_kernel<<<9092,256,0,stream>>>(cursor,
        w1, wT1, w2, wT2, w3, wT3,
        b1,g1,bb1,m1,v1, b2,g2,bb2,m2,v2, s1,t1,s2,t2,
        rel, lsc, shf, lsg, dparams, imgf, in0);

    conv1_fill_kernel<<<NCONV1 + NFILL,256,0,stream>>>(
        in0, wT1, s1, t1, h1, zpad16, dparams, vids, cursor, records);
    conv_mfma<9,true ,256><<<dim3(264,2),256,0,stream>>>(h1,  wT2, s2, t2, h2, zpad16);
    conv_mfma<1,false,128><<<dim3(264,1),256,0,stream>>>(h2,  wT3, s1, b3, feat16, zpad16);

    gather_kernel<<<4096,256,0,stream>>>(records, cursor, feat16, bev_t);
    transpose_out<<<dim3(512,4),256,0,stream>>>(bev_t, (float*)d_out);
}